// Round 1
// baseline (1941.366 us; speedup 1.0000x reference)
//
#include <hip/hip_runtime.h>
#include <hip/hip_bf16.h>
#include <cmath>

#define EMBED_DIM 128
#define TEMP_DIM  32
#define DATE_SCALE 1825.0f
#define LN_EPS 1e-5f

__device__ __forceinline__ float gelu_exact(float x) {
    // jax.nn.gelu(approximate=False): x * 0.5 * (1 + erf(x/sqrt(2)))
    return 0.5f * x * (1.0f + erff(x * 0.70710678118654752f));
}

__device__ __forceinline__ unsigned short f32_to_bf16(float f) {
    union { float f; unsigned int u; } v; v.f = f;
    unsigned int u = v.u;
    unsigned int r = u + 0x7FFFu + ((u >> 16) & 1u);  // round-to-nearest-even
    return (unsigned short)(r >> 16);
}
__device__ __forceinline__ float bf16_to_f32(unsigned short h) {
    union { unsigned int u; float f; } v; v.u = ((unsigned int)h) << 16;
    return v.f;
}

// One block per batch row; thread t handles position l = chunk*256 + t.
// LDS: per-thread GELU(LN1(h1)) row in bf16 (stride 129 -> <=2-way bank alias, free)
//      + 4x128 fp32 wave partials for the pooled sum.
__global__ __launch_bounds__(256, 2) void encoder_kernel(
    const int*   __restrict__ tids,   const float* __restrict__ dates,
    const int*   __restrict__ lengths,
    const float* __restrict__ emb,
    const float* __restrict__ tp_w,   const float* __restrict__ tp_b,
    const float* __restrict__ tp_lnw, const float* __restrict__ tp_lnb,
    const float* __restrict__ w1,     const float* __restrict__ b1,
    const float* __restrict__ ln1w,   const float* __restrict__ ln1b,
    const float* __restrict__ w2,     const float* __restrict__ b2,
    const float* __restrict__ ln2w,   const float* __restrict__ ln2b,
    float* __restrict__ out, int B, int L)
{
    const int b    = blockIdx.x;
    const int tid  = threadIdx.x;
    const int lane = tid & 63;
    const int wid  = tid >> 6;

    __shared__ unsigned short g_lds[256 * 129];
    __shared__ float part[4 * 128];

    part[tid] = 0.0f;
    part[tid + 256] = 0.0f;
    __syncthreads();

    const int len = min(max(lengths[b], 0), L);

    // Uniform sums for the closed-form temporal LN statistics:
    // t_j = dn*w_j + b_j ; mean/var are quadratics in dn.
    float Sw = 0.f, Sb = 0.f, Sww = 0.f, Swb = 0.f, Sbb = 0.f;
    #pragma unroll
    for (int j = 0; j < TEMP_DIM; ++j) {
        const float w = tp_w[j], bb = tp_b[j];
        Sw += w; Sb += bb; Sww += w * w; Swb += w * bb; Sbb += bb * bb;
    }

    for (int l0 = 0; l0 < L; l0 += 256) {
        const int  l      = l0 + tid;
        const bool active = (l < len);
        if (__ballot(active) == 0ull) continue;  // whole wave idle -> skip

        float h[128];
        #pragma unroll
        for (int d = 0; d < 128; ++d) h[d] = 0.0f;

        if (active) {
            const long long pos = (long long)b * L + l;
            const float dn = dates[pos] * (1.0f / DATE_SCALE);
            const int   id = tids[pos];

            // temporal LN stats (exact, closed form)
            const float tm = (dn * Sw + Sb) * (1.0f / TEMP_DIM);
            float tv = (dn * dn * Sww + 2.0f * dn * Swb + Sbb) * (1.0f / TEMP_DIM) - tm * tm;
            tv = fmaxf(tv, 0.0f);
            const float trstd = rsqrtf(tv + LN_EPS);

            // ---------- GEMM1: embedding part (k = 0..127) ----------
            #pragma unroll
            for (int d = 0; d < 128; ++d) h[d] = b1[d];   // uniform scalar loads
            const float4* embrow = reinterpret_cast<const float4*>(emb + (long long)id * EMBED_DIM);
            for (int k4 = 0; k4 < EMBED_DIM / 4; ++k4) {
                const float4 c4 = embrow[k4];
                const float* wr = w1 + (k4 * 4) * EMBED_DIM;
                #pragma unroll
                for (int d = 0; d < 128; ++d) h[d] = fmaf(c4.x, wr[d], h[d]);
                #pragma unroll
                for (int d = 0; d < 128; ++d) h[d] = fmaf(c4.y, wr[EMBED_DIM + d], h[d]);
                #pragma unroll
                for (int d = 0; d < 128; ++d) h[d] = fmaf(c4.z, wr[2 * EMBED_DIM + d], h[d]);
                #pragma unroll
                for (int d = 0; d < 128; ++d) h[d] = fmaf(c4.w, wr[3 * EMBED_DIM + d], h[d]);
            }
            // ---------- GEMM1: temporal part (k = 128..159), t_j recomputed ----------
            for (int j = 0; j < TEMP_DIM; ++j) {
                const float raw = fmaf(dn, tp_w[j], tp_b[j]);
                const float y   = fmaf((raw - tm) * trstd, tp_lnw[j], tp_lnb[j]);
                const float t   = gelu_exact(y);
                const float* wr = w1 + (EMBED_DIM + j) * EMBED_DIM;
                #pragma unroll
                for (int d = 0; d < 128; ++d) h[d] = fmaf(t, wr[d], h[d]);
            }

            // ---------- LN1 + GELU -> bf16 row in LDS ----------
            float m = 0.f;
            #pragma unroll
            for (int d = 0; d < 128; ++d) m += h[d];
            m *= (1.0f / 128.0f);
            float v = 0.f;
            #pragma unroll
            for (int d = 0; d < 128; ++d) { const float df = h[d] - m; v += df * df; }
            v *= (1.0f / 128.0f);
            const float rstd = rsqrtf(v + LN_EPS);
            unsigned short* grow = &g_lds[tid * 129];
            #pragma unroll
            for (int d = 0; d < 128; ++d) {
                const float y = fmaf((h[d] - m) * rstd, ln1w[d], ln1b[d]);
                grow[d] = f32_to_bf16(gelu_exact(y));
            }

            // ---------- GEMM2 ----------
            #pragma unroll
            for (int d = 0; d < 128; ++d) h[d] = b2[d];
            for (int k = 0; k < EMBED_DIM; k += 2) {
                const float g0 = bf16_to_f32(grow[k]);
                const float g1 = bf16_to_f32(grow[k + 1]);
                const float* wr = w2 + (long long)k * EMBED_DIM;
                #pragma unroll
                for (int d = 0; d < 128; ++d) h[d] = fmaf(g0, wr[d], h[d]);
                #pragma unroll
                for (int d = 0; d < 128; ++d) h[d] = fmaf(g1, wr[EMBED_DIM + d], h[d]);
            }

            // ---------- LN2 ----------
            float m2 = 0.f;
            #pragma unroll
            for (int d = 0; d < 128; ++d) m2 += h[d];
            m2 *= (1.0f / 128.0f);
            float v2 = 0.f;
            #pragma unroll
            for (int d = 0; d < 128; ++d) { const float df = h[d] - m2; v2 += df * df; }
            v2 *= (1.0f / 128.0f);
            const float rstd2 = rsqrtf(v2 + LN_EPS);
            #pragma unroll
            for (int d = 0; d < 128; ++d) h[d] = fmaf((h[d] - m2) * rstd2, ln2w[d], ln2b[d]);
        }

        // ---------- masked pooled sum: wave butterfly -> LDS partials ----------
        #pragma unroll
        for (int d = 0; d < 128; ++d) {
            float v = h[d];
            v += __shfl_xor(v, 32);
            v += __shfl_xor(v, 16);
            v += __shfl_xor(v, 8);
            v += __shfl_xor(v, 4);
            v += __shfl_xor(v, 2);
            v += __shfl_xor(v, 1);
            if (lane == 0) part[wid * 128 + d] += v;
        }
    }

    __syncthreads();
    if (tid < 128) {
        const float s = part[tid] + part[128 + tid] + part[256 + tid] + part[384 + tid];
        out[(long long)b * 128 + tid] = (len > 0) ? (s / (float)len) : 0.0f;
    }
}

extern "C" void kernel_launch(void* const* d_in, const int* in_sizes, int n_in,
                              void* d_out, int out_size, void* d_ws, size_t ws_size,
                              hipStream_t stream) {
    const int*   tids    = (const int*)  d_in[0];
    const float* dates   = (const float*)d_in[1];
    const int*   lengths = (const int*)  d_in[2];
    const float* emb     = (const float*)d_in[3];
    const float* tp_w    = (const float*)d_in[4];
    const float* tp_b    = (const float*)d_in[5];
    const float* tp_lnw  = (const float*)d_in[6];
    const float* tp_lnb  = (const float*)d_in[7];
    const float* w1      = (const float*)d_in[8];
    const float* b1      = (const float*)d_in[9];
    const float* ln1w    = (const float*)d_in[10];
    const float* ln1b    = (const float*)d_in[11];
    const float* w2      = (const float*)d_in[12];
    const float* b2      = (const float*)d_in[13];
    const float* ln2w    = (const float*)d_in[14];
    const float* ln2b    = (const float*)d_in[15];
    float* out = (float*)d_out;

    const int B = in_sizes[2];
    const int L = in_sizes[0] / B;

    hipLaunchKernelGGL(encoder_kernel, dim3(B), dim3(256), 0, stream,
                       tids, dates, lengths, emb, tp_w, tp_b, tp_lnw, tp_lnb,
                       w1, b1, ln1w, ln1b, w2, b2, ln2w, ln2b, out, B, L);
}

// Round 2
// 278.351 us; speedup vs baseline: 6.9745x; 6.9745x over previous
//
#include <hip/hip_runtime.h>
#include <cmath>

#define LN_EPS 1e-5f

typedef float  f32x4  __attribute__((ext_vector_type(4)));
typedef short  short8 __attribute__((ext_vector_type(8)));
typedef unsigned int uint4v __attribute__((ext_vector_type(4)));

// ws layout (bytes):
//   w1f  : 5*8*64*16 = 40960   (uint4 frags, B-operand layout, bf16)
//   w2f  : 4*8*64*16 = 32768
//   emb16: NUM_TYPES*128*2     (row-major bf16)
#define W1F_U4 2560   // 5*8*64
#define W2F_U4 2048   // 4*8*64

__device__ __forceinline__ unsigned short f32_bf16_rne(float f) {
    union { float f; unsigned u; } v; v.f = f;
    unsigned r = v.u + 0x7FFFu + ((v.u >> 16) & 1u);
    return (unsigned short)(r >> 16);
}

// exact-erf GELU via Abramowitz&Stegun 7.1.26 (|err| <= 1.5e-7)
__device__ __forceinline__ float gelu_f(float x) {
    float ax = fabsf(x);
    float a  = ax * 0.70710678118654752f;          // |x|/sqrt(2)
    float t  = __builtin_amdgcn_rcpf(fmaf(0.3275911f, a, 1.0f));
    float p  = t * fmaf(t, fmaf(t, fmaf(t, fmaf(t, 1.061405429f, -1.453152027f),
                                        1.421413741f), -0.284496736f), 0.254829592f);
    float e  = __builtin_amdgcn_exp2f(-1.44269504089f * a * a);
    float E  = fmaf(-p, e, 1.0f);                  // erf(|x|/sqrt2)
    return 0.5f * fmaf(ax, E, x);                  // 0.5*(x + |x|*erf)
}

// -------- prep: swizzle w1/w2 into MFMA B-fragment layout (bf16), convert emb
//          to bf16 rows, and zero d_out (pool uses atomics). Re-run every call.
__global__ void prep_kernel(const float* __restrict__ w1, const float* __restrict__ w2,
                            const float* __restrict__ emb, float* __restrict__ out,
                            unsigned* __restrict__ ws, int emb_pairs, int out4) {
    const int tid = blockIdx.x * 256 + threadIdx.x;   // 8192 threads
    uint4v* w1f = (uint4v*)ws;
    uint4v* w2f = w1f + W1F_U4;
    unsigned* emb16 = (unsigned*)(w2f + W2F_U4);

    for (int i = tid; i < W1F_U4; i += 8192) {        // frag(kt,nt,lane): B[k][n]
        const int lane = i & 63, nt = (i >> 6) & 7, kt = i >> 9;
        const int k0 = kt * 32 + (lane >> 4) * 8, n = nt * 16 + (lane & 15);
        uint4v r;
        #pragma unroll
        for (int j2 = 0; j2 < 4; ++j2) {
            unsigned lo = f32_bf16_rne(w1[(k0 + 2 * j2) * 128 + n]);
            unsigned hi = f32_bf16_rne(w1[(k0 + 2 * j2 + 1) * 128 + n]);
            r[j2] = lo | (hi << 16);
        }
        w1f[i] = r;
    }
    for (int i = tid; i < W2F_U4; i += 8192) {
        const int lane = i & 63, nt = (i >> 6) & 7, kt = i >> 9;
        const int k0 = kt * 32 + (lane >> 4) * 8, n = nt * 16 + (lane & 15);
        uint4v r;
        #pragma unroll
        for (int j2 = 0; j2 < 4; ++j2) {
            unsigned lo = f32_bf16_rne(w2[(k0 + 2 * j2) * 128 + n]);
            unsigned hi = f32_bf16_rne(w2[(k0 + 2 * j2 + 1) * 128 + n]);
            r[j2] = lo | (hi << 16);
        }
        w2f[i] = r;
    }
    for (int i = tid; i < emb_pairs; i += 8192) {
        unsigned lo = f32_bf16_rne(emb[2 * i]);
        unsigned hi = f32_bf16_rne(emb[2 * i + 1]);
        emb16[i] = lo | (hi << 16);
    }
    f32x4 z = {0.f, 0.f, 0.f, 0.f};
    for (int i = tid; i < out4; i += 8192) ((f32x4*)out)[i] = z;
}

// -------- main: one block per batch row, 4 waves x 64 positions (M padded to 256).
__global__ __launch_bounds__(256, 2) void encoder_mfma(
    const int*   __restrict__ tids,  const float* __restrict__ dates,
    const int*   __restrict__ lengths,
    const float* __restrict__ tp_w,  const float* __restrict__ tp_b,
    const float* __restrict__ tp_lnw,const float* __restrict__ tp_lnb,
    const float* __restrict__ b1,    const float* __restrict__ ln1w, const float* __restrict__ ln1b,
    const float* __restrict__ b2,    const float* __restrict__ ln2w, const float* __restrict__ ln2b,
    const unsigned* __restrict__ ws, float* __restrict__ out, int L)
{
    // per-wave C-layout -> A-layout transpose scratch: [wave][mt][kt2][lane][j]
    __shared__ unsigned short a2[4][4][4][64][8];   // exactly 64 KB

    const int b = blockIdx.x;
    const int tid = threadIdx.x;
    const int lane = tid & 63, w = tid >> 6;
    const int c = lane & 15, g = lane >> 4;
    const int len = min(max(lengths[b], 0), L);
    const int R0 = w * 64;
    if (R0 >= len) return;                           // wave-uniform exit

    const uint4v* w1f = (const uint4v*)ws;
    const uint4v* w2f = w1f + W1F_U4;
    const unsigned short* emb16 = (const unsigned short*)(w2f + W2F_U4);

    // uniform temporal-LN closed-form sums (scalar loads)
    float Sw = 0.f, Sb = 0.f, Sww = 0.f, Swb = 0.f, Sbb = 0.f;
    for (int j = 0; j < 32; ++j) {
        const float ww = tp_w[j], bb = tp_b[j];
        Sw += ww; Sb += bb; Sww += ww * ww; Swb += ww * bb; Sbb += bb * bb;
    }

    int   id[4]; float dn[4]; bool amt[4];
    #pragma unroll
    for (int mt = 0; mt < 4; ++mt) {
        const int p  = R0 + mt * 16 + c;
        const int pc = min(p, L - 1);
        id[mt]  = tids[b * L + pc];
        dn[mt]  = dates[b * L + pc] * (1.f / 1825.f);
        amt[mt] = (R0 + mt * 16) < len;              // wave-uniform
    }

    // temporal A-frags (row = c, k-chunk = g*8..g*8+7)
    short8 tfrag[4];
    {
        float tw[8], tb[8], tlw[8], tlb[8];
        const int j0 = g * 8;
        #pragma unroll
        for (int jj = 0; jj < 8; ++jj) {
            tw[jj] = tp_w[j0 + jj]; tb[jj] = tp_b[j0 + jj];
            tlw[jj] = tp_lnw[j0 + jj]; tlb[jj] = tp_lnb[j0 + jj];
        }
        #pragma unroll
        for (int mt = 0; mt < 4; ++mt) {
            const float d  = dn[mt];
            const float tm = fmaf(d, Sw, Sb) * (1.f / 32.f);
            float tv = fmaf(d * d, Sww, fmaf(2.f * d, Swb, Sbb)) * (1.f / 32.f) - tm * tm;
            const float trs = rsqrtf(fmaxf(tv, 0.f) + LN_EPS);
            uint4v r;
            #pragma unroll
            for (int j2 = 0; j2 < 4; ++j2) {
                const float y0 = fmaf((fmaf(d, tw[2*j2],   tb[2*j2])   - tm) * trs, tlw[2*j2],   tlb[2*j2]);
                const float y1 = fmaf((fmaf(d, tw[2*j2+1], tb[2*j2+1]) - tm) * trs, tlw[2*j2+1], tlb[2*j2+1]);
                r[j2] = (unsigned)f32_bf16_rne(gelu_f(y0)) | ((unsigned)f32_bf16_rne(gelu_f(y1)) << 16);
            }
            union { uint4v u; short8 s; } cv; cv.u = r;
            tfrag[mt] = cv.s;
        }
    }

    // ---------------- GEMM1: [4mt x 16][K=160] @ w1 -> acc ----------------
    f32x4 acc[4][8];
    #pragma unroll
    for (int mt = 0; mt < 4; ++mt)
        #pragma unroll
        for (int nt = 0; nt < 8; ++nt) acc[mt][nt] = (f32x4){0.f, 0.f, 0.f, 0.f};

    #pragma unroll
    for (int kt = 0; kt < 5; ++kt) {
        short8 af[4];
        if (kt < 4) {
            #pragma unroll
            for (int mt = 0; mt < 4; ++mt)
                af[mt] = *(const short8*)(emb16 + id[mt] * 128 + kt * 32 + g * 8);
        } else {
            #pragma unroll
            for (int mt = 0; mt < 4; ++mt) af[mt] = tfrag[mt];
        }
        #pragma unroll
        for (int nt = 0; nt < 8; ++nt) {
            const short8 bf = ((const short8*)w1f)[(kt * 8 + nt) * 64 + lane];
            #pragma unroll
            for (int mt = 0; mt < 4; ++mt)
                acc[mt][nt] = __builtin_amdgcn_mfma_f32_16x16x32_bf16(af[mt], bf, acc[mt][nt], 0, 0, 0);
        }
    }

    // ---------------- epilogue 1: +b1, LN1, GELU -> bf16 a2 ----------------
    {
        float l1w[8], l1b[8], bb1[8];
        #pragma unroll
        for (int nt = 0; nt < 8; ++nt) {
            l1w[nt] = ln1w[nt * 16 + c]; l1b[nt] = ln1b[nt * 16 + c]; bb1[nt] = b1[nt * 16 + c];
        }
        #pragma unroll
        for (int mt = 0; mt < 4; ++mt) {
            if (!amt[mt]) continue;                  // wave-uniform skip
            #pragma unroll
            for (int r = 0; r < 4; ++r) {
                float v[8], s = 0.f, q = 0.f;
                #pragma unroll
                for (int nt = 0; nt < 8; ++nt) {
                    v[nt] = acc[mt][nt][r] + bb1[nt];
                    s += v[nt]; q = fmaf(v[nt], v[nt], q);
                }
                s += __shfl_xor(s, 1); q += __shfl_xor(q, 1);
                s += __shfl_xor(s, 2); q += __shfl_xor(q, 2);
                s += __shfl_xor(s, 4); q += __shfl_xor(q, 4);
                s += __shfl_xor(s, 8); q += __shfl_xor(q, 8);
                const float mean = s * (1.f / 128.f);
                const float var  = fmaxf(q * (1.f / 128.f) - mean * mean, 0.f);
                const float rstd = rsqrtf(var + LN_EPS);
                const int mrow = 4 * g + r;
                #pragma unroll
                for (int nt = 0; nt < 8; ++nt) {
                    const float y = fmaf((v[nt] - mean) * rstd, l1w[nt], l1b[nt]);
                    const unsigned short hv = f32_bf16_rne(gelu_f(y));
                    const int kcol = nt * 16 + c;
                    a2[w][mt][kcol >> 5][((kcol >> 3) & 3) * 16 + mrow][kcol & 7] = hv;
                }
            }
        }
    }

    // ---------------- GEMM2: a2 @ w2 -> acc2 ----------------
    f32x4 acc2[4][8];
    #pragma unroll
    for (int mt = 0; mt < 4; ++mt)
        #pragma unroll
        for (int nt = 0; nt < 8; ++nt) acc2[mt][nt] = (f32x4){0.f, 0.f, 0.f, 0.f};

    #pragma unroll
    for (int kt2 = 0; kt2 < 4; ++kt2) {
        short8 af[4];
        #pragma unroll
        for (int mt = 0; mt < 4; ++mt)
            __builtin_memcpy(&af[mt], &a2[w][mt][kt2][lane][0], 16);
        #pragma unroll
        for (int nt = 0; nt < 8; ++nt) {
            const short8 bf = ((const short8*)w2f)[(kt2 * 8 + nt) * 64 + lane];
            #pragma unroll
            for (int mt = 0; mt < 4; ++mt)
                acc2[mt][nt] = __builtin_amdgcn_mfma_f32_16x16x32_bf16(af[mt], bf, acc2[mt][nt], 0, 0, 0);
        }
    }

    // ---------------- epilogue 2: +b2, LN2, mask, pool ----------------
    {
        float l2w[8], l2b[8], bb2[8], pool[8];
        #pragma unroll
        for (int nt = 0; nt < 8; ++nt) {
            l2w[nt] = ln2w[nt * 16 + c]; l2b[nt] = ln2b[nt * 16 + c]; bb2[nt] = b2[nt * 16 + c];
            pool[nt] = 0.f;
        }
        #pragma unroll
        for (int mt = 0; mt < 4; ++mt) {
            if (!amt[mt]) continue;
            #pragma unroll
            for (int r = 0; r < 4; ++r) {
                float v[8], s = 0.f, q = 0.f;
                #pragma unroll
                for (int nt = 0; nt < 8; ++nt) {
                    v[nt] = acc2[mt][nt][r] + bb2[nt];
                    s += v[nt]; q = fmaf(v[nt], v[nt], q);
                }
                s += __shfl_xor(s, 1); q += __shfl_xor(q, 1);
                s += __shfl_xor(s, 2); q += __shfl_xor(q, 2);
                s += __shfl_xor(s, 4); q += __shfl_xor(q, 4);
                s += __shfl_xor(s, 8); q += __shfl_xor(q, 8);
                const float mean = s * (1.f / 128.f);
                const float var  = fmaxf(q * (1.f / 128.f) - mean * mean, 0.f);
                const float rstd = rsqrtf(var + LN_EPS);
                const int p = R0 + mt * 16 + 4 * g + r;
                const float msk = (p < len) ? 1.f : 0.f;
                #pragma unroll
                for (int nt = 0; nt < 8; ++nt) {
                    const float y = fmaf((v[nt] - mean) * rstd, l2w[nt], l2b[nt]);
                    pool[nt] = fmaf(y, msk, pool[nt]);
                }
            }
        }
        #pragma unroll
        for (int nt = 0; nt < 8; ++nt) {
            float t = pool[nt];
            t += __shfl_xor(t, 16);
            t += __shfl_xor(t, 32);
            pool[nt] = t;
        }
        if (g == 0) {
            const float inv = 1.f / (float)len;      // len >= 1 here
            #pragma unroll
            for (int nt = 0; nt < 8; ++nt)
                atomicAdd(&out[b * 128 + nt * 16 + c], pool[nt] * inv);
        }
    }
}

extern "C" void kernel_launch(void* const* d_in, const int* in_sizes, int n_in,
                              void* d_out, int out_size, void* d_ws, size_t ws_size,
                              hipStream_t stream) {
    const int*   tids    = (const int*)  d_in[0];
    const float* dates   = (const float*)d_in[1];
    const int*   lengths = (const int*)  d_in[2];
    const float* emb     = (const float*)d_in[3];
    const float* tp_w    = (const float*)d_in[4];
    const float* tp_b    = (const float*)d_in[5];
    const float* tp_lnw  = (const float*)d_in[6];
    const float* tp_lnb  = (const float*)d_in[7];
    const float* w1      = (const float*)d_in[8];
    const float* b1      = (const float*)d_in[9];
    const float* ln1w    = (const float*)d_in[10];
    const float* ln1b    = (const float*)d_in[11];
    const float* w2      = (const float*)d_in[12];
    const float* b2      = (const float*)d_in[13];
    const float* ln2w    = (const float*)d_in[14];
    const float* ln2b    = (const float*)d_in[15];
    float* out = (float*)d_out;

    const int B = in_sizes[2];
    const int L = in_sizes[0] / B;
    const int emb_pairs = in_sizes[3] / 2;

    hipLaunchKernelGGL(prep_kernel, dim3(32), dim3(256), 0, stream,
                       w1, w2, emb, out, (unsigned*)d_ws, emb_pairs, out_size / 4);
    hipLaunchKernelGGL(encoder_mfma, dim3(B), dim3(256), 0, stream,
                       tids, dates, lengths, tp_w, tp_b, tp_lnw, tp_lnb,
                       b1, ln1w, ln1b, b2, ln2w, ln2b,
                       (const unsigned*)d_ws, out, L);
}